// Round 3
// baseline (316.330 us; speedup 1.0000x reference)
//
#include <hip/hip_runtime.h>
#include <math.h>

using u16 = unsigned short;
typedef __attribute__((ext_vector_type(8))) short short8;
typedef __attribute__((ext_vector_type(16))) float floatx16;

constexpr int Bc = 32, Nn = 500, Mm = 500, Dd = 256;
constexpr float LOGIT_CLIP = 10.0f;
constexpr float INV_SQRT_D = 1.0f / 16.0f;

__device__ __forceinline__ floatx16 mfma32(short8 a, short8 b, floatx16 c) {
    return __builtin_amdgcn_mfma_f32_32x32x16_bf16(a, b, c, 0, 0, 0);
}

__device__ __forceinline__ floatx16 zero16() {
    floatx16 v = {0.f,0.f,0.f,0.f,0.f,0.f,0.f,0.f,0.f,0.f,0.f,0.f,0.f,0.f,0.f,0.f};
    return v;
}

// split fp32 x into bf16 hi (RTN) + bf16 lo (RTN of residual): x ~= hi + lo
__device__ __forceinline__ void split1(float x, u16& h, u16& l) {
    unsigned u = __float_as_uint(x);
    unsigned rh = (u + 0x7FFFu + ((u >> 16) & 1u)) & 0xFFFF0000u;
    float fh = __uint_as_float(rh);
    float fl = x - fh;
    unsigned ul = __float_as_uint(fl);
    unsigned rl = ul + 0x7FFFu + ((ul >> 16) & 1u);
    h = (u16)(rh >> 16);
    l = (u16)(rl >> 16);
}

__device__ __forceinline__ u16 bf16rtn(float x) {
    unsigned u = __float_as_uint(x);
    return (u16)((u + 0x7FFFu + ((u >> 16) & 1u)) >> 16);
}

__device__ __forceinline__ float fast_tanh(float x) {
    return 1.0f - 2.0f / (__expf(2.0f * x) + 1.0f);
}

__device__ __forceinline__ void split8(const float4& a, const float4& c,
                                       short8& hv, short8& lv) {
    u16 hh, ll;
    split1(a.x, hh, ll); hv[0] = (short)hh; lv[0] = (short)ll;
    split1(a.y, hh, ll); hv[1] = (short)hh; lv[1] = (short)ll;
    split1(a.z, hh, ll); hv[2] = (short)hh; lv[2] = (short)ll;
    split1(a.w, hh, ll); hv[3] = (short)hh; lv[3] = (short)ll;
    split1(c.x, hh, ll); hv[4] = (short)hh; lv[4] = (short)ll;
    split1(c.y, hh, ll); hv[5] = (short)hh; lv[5] = (short)ll;
    split1(c.z, hh, ll); hv[6] = (short)hh; lv[6] = (short)ll;
    split1(c.w, hh, ll); hv[7] = (short)hh; lv[7] = (short)ll;
}

// ===========================================================================
// Packed fragment layouts (u16 units), fragment = [lane(64)][e(8)] = 512 u16:
//   element (row r, col d) lives at lane=((d>>3)&1)<<5 | (r&31), e = d&7.
//   tile stride: 16 dc-chunks x 2 arr(H/L) x 512 = 16384 u16 per 32-row tile.
// PKW [w(4)][dt(8)]  : weights,  w = {Wk,Wv,Wq0,Wq1}, rows = out-dim.
// PKJ [b][mt(16)]    : jobs,   rows m (zero-padded to 512).
// PKQ0/PKQ1 [b][nt]  : q0/q1,  rows n (zero-padded).
// PKC [b][nt(16)]    : aafm,   rows n (pad rows garbage -> masked in k4).
// PKA [b][nt(16)][mc(32)][512] : expb (n-rows x m-cols), m zero-padded.
// PKB [b][dt(8)][mc(32)][arr(4: ekH,ekL,ekvH,ekvL)][512] : ek/ekv transposed.
// ===========================================================================

// ---------------------------------------------------------------------------
// K0w_pk: weights fp32 -> packed bf16 hi/lo fragments
// ---------------------------------------------------------------------------
__global__ __launch_bounds__(256) void k0w_pk(const float* __restrict__ s0,
                                              const float* __restrict__ s1,
                                              const float* __restrict__ s2,
                                              const float* __restrict__ s3,
                                              u16* __restrict__ pkw) {
    const float* s = blockIdx.y == 0 ? s0 : blockIdx.y == 1 ? s1 :
                     blockIdx.y == 2 ? s2 : s3;
    const int w = blockIdx.y;
    const int flat = (blockIdx.x * 256 + threadIdx.x) * 8;   // 0..65535
    const int i = flat >> 8, j0 = flat & 255;
    float4 a = *(const float4*)&s[flat];
    float4 c = *(const float4*)&s[flat + 4];
    short8 hv, lv;
    split8(a, c, hv, lv);
    const int dt = i >> 5, i31 = i & 31, dc = j0 >> 4, hp = (j0 >> 3) & 1;
    const size_t off = (size_t)(w * 8 + dt) * 16384 + (size_t)dc * 1024
                     + (size_t)((hp << 5) | i31) * 8;
    *(short8*)&pkw[off] = hv;
    *(short8*)&pkw[off + 512] = lv;
}

// ---------------------------------------------------------------------------
// K0pk3: jobs/q0/q1 fp32 -> packed bf16 hi/lo fragments, rows zero-padded 512
// ---------------------------------------------------------------------------
__global__ __launch_bounds__(256) void k0pk3(const float* __restrict__ s0,
                                             const float* __restrict__ s1,
                                             const float* __restrict__ s2,
                                             u16* __restrict__ d0,
                                             u16* __restrict__ d1,
                                             u16* __restrict__ d2) {
    const float* s = blockIdx.y == 0 ? s0 : blockIdx.y == 1 ? s1 : s2;
    u16* d = blockIdx.y == 0 ? d0 : blockIdx.y == 1 ? d1 : d2;
    const int bx = blockIdx.x;           // 0..2047
    const int b = bx >> 6;
    const int chunk = bx & 63;
    const int flat = threadIdx.x * 8;    // 0..2047
    const int lr = flat >> 8;            // 0..7
    const int j0 = flat & 255;
    const int pr = chunk * 8 + lr;       // padded row 0..511
    short8 hv = {0,0,0,0,0,0,0,0}, lv = {0,0,0,0,0,0,0,0};
    if (pr < Nn) {
        const size_t o = ((size_t)b * Nn + pr) * Dd + j0;
        float4 a = *(const float4*)&s[o];
        float4 c = *(const float4*)&s[o + 4];
        split8(a, c, hv, lv);
    }
    const int mt = pr >> 5, r31 = pr & 31;
    const int dc = j0 >> 4, hp = (j0 >> 3) & 1;
    const size_t off = (size_t)(b * 16 + mt) * 16384 + (size_t)dc * 1024
                     + (size_t)((hp << 5) | r31) * 8;
    *(short8*)&d[off] = hv;
    *(short8*)&d[off + 512] = lv;
}

// ---------------------------------------------------------------------------
// KEXP_PK: expb fragment-packed.
// ---------------------------------------------------------------------------
__global__ __launch_bounds__(256) void kexp_pk(const float* __restrict__ cost,
                                               const float* __restrict__ mask,
                                               const float* __restrict__ alpha1,
                                               const float* __restrict__ lsc,
                                               u16* __restrict__ pka) {
    __shared__ u16 tile[32][520];
    const float a1ls = alpha1[0] * lsc[0];
    const int b = blockIdx.x >> 4, nt = blockIdx.x & 15;
    const int t = threadIdx.x;
#pragma unroll
    for (int q = 0; q < 8; ++q) {
        const int flat = (q << 11) + (t << 3);
        const int nl = flat >> 9, m = flat & 511;
        const int n = min(nt * 32 + nl, Nn - 1);
        const size_t o = ((size_t)b * Nn + n) * Mm + m;
        ushort4 w0 = {0, 0, 0, 0}, w1 = {0, 0, 0, 0};
        if (m <= 488) {
            float4 c0 = *(const float4*)&cost[o];
            float4 c1 = *(const float4*)&cost[o + 4];
            float4 k0 = *(const float4*)&mask[o];
            float4 k1 = *(const float4*)&mask[o + 4];
            w0.x = bf16rtn(__expf(fmaf(-a1ls, c0.x, k0.x)));
            w0.y = bf16rtn(__expf(fmaf(-a1ls, c0.y, k0.y)));
            w0.z = bf16rtn(__expf(fmaf(-a1ls, c0.z, k0.z)));
            w0.w = bf16rtn(__expf(fmaf(-a1ls, c0.w, k0.w)));
            w1.x = bf16rtn(__expf(fmaf(-a1ls, c1.x, k1.x)));
            w1.y = bf16rtn(__expf(fmaf(-a1ls, c1.y, k1.y)));
            w1.z = bf16rtn(__expf(fmaf(-a1ls, c1.z, k1.z)));
            w1.w = bf16rtn(__expf(fmaf(-a1ls, c1.w, k1.w)));
        } else if (m == 496) {
            float4 c0 = *(const float4*)&cost[o];
            float4 k0 = *(const float4*)&mask[o];
            w0.x = bf16rtn(__expf(fmaf(-a1ls, c0.x, k0.x)));
            w0.y = bf16rtn(__expf(fmaf(-a1ls, c0.y, k0.y)));
            w0.z = bf16rtn(__expf(fmaf(-a1ls, c0.z, k0.z)));
            w0.w = bf16rtn(__expf(fmaf(-a1ls, c0.w, k0.w)));
        }
        *(ushort4*)&tile[nl][m] = w0;
        *(ushort4*)&tile[nl][m + 4] = w1;
    }
    __syncthreads();
    const int lane = t & 63, wvv = t >> 6;
    const int n31 = lane & 31, hh = lane >> 5;
    const size_t pbase = (size_t)(b * 16 + nt) * 16384 + (size_t)lane * 8;
#pragma unroll
    for (int q = 0; q < 8; ++q) {
        const int mc = wvv * 8 + q;
        short8 v = *(const short8*)&tile[n31][mc * 16 + hh * 8];
        *(short8*)&pka[pbase + (size_t)mc * 512] = v;
    }
}

// ---------------------------------------------------------------------------
// K1: k/v = jobs@Wk^T/Wv^T. m-split: each wave owns ONE 32-m tile x one dt.
// Grid (16,2,32) x 4 waves = 4096 waves (4/SIMD). Writes PKB packed.
// ---------------------------------------------------------------------------
__global__ __launch_bounds__(256) void k1_kv(const u16* __restrict__ pkj,
                                             const u16* __restrict__ pkw,
                                             u16* __restrict__ pkb) {
    const int lane = threadIdx.x & 63, wv = threadIdx.x >> 6;
    const int l31 = lane & 31, h = lane >> 5;
    const int b = blockIdx.z;
    const int dt = blockIdx.y * 4 + wv;      // 0..7
    const int mt = blockIdx.x;               // 0..15, M0 = mt*32
    const int M0 = mt * 32;

    const size_t wk  = (size_t)dt * 16384 + (size_t)lane * 8;         // Wk
    const size_t wvb = (size_t)(8 + dt) * 16384 + (size_t)lane * 8;   // Wv
    const size_t jb  = (size_t)(b * 16 + mt) * 16384 + (size_t)lane * 8;

    floatx16 ak = zero16(), av = zero16();

    short8 buf[3][6];
#define K1L(S, DC) { \
    buf[S][0] = *(const short8*)(pkw + wk  + (size_t)(DC) * 1024); \
    buf[S][1] = *(const short8*)(pkw + wk  + (size_t)(DC) * 1024 + 512); \
    buf[S][2] = *(const short8*)(pkw + wvb + (size_t)(DC) * 1024); \
    buf[S][3] = *(const short8*)(pkw + wvb + (size_t)(DC) * 1024 + 512); \
    buf[S][4] = *(const short8*)(pkj + jb  + (size_t)(DC) * 1024); \
    buf[S][5] = *(const short8*)(pkj + jb  + (size_t)(DC) * 1024 + 512); }

    K1L(0, 0)
    K1L(1, 1)
#pragma unroll
    for (int it = 0; it < 16; ++it) {
        if (it + 2 < 16) { K1L((it + 2) % 3, it + 2) }
        const int c = it % 3;
        ak = mfma32(buf[c][0], buf[c][4], ak);
        ak = mfma32(buf[c][0], buf[c][5], ak);
        ak = mfma32(buf[c][1], buf[c][4], ak);
        av = mfma32(buf[c][2], buf[c][4], av);
        av = mfma32(buf[c][2], buf[c][5], av);
        av = mfma32(buf[c][3], buf[c][4], av);
    }
#undef K1L

    // ---- epilogue: packed-fragment scatter (zero-fill padded m) ----
    const int hp = (l31 >> 3) & 1, ee = l31 & 7, mcl = l31 >> 4;
    const size_t sb0 = ((size_t)b * 8 + dt) * 65536
                     + (size_t)(mt * 2 + mcl) * 2048 + (size_t)hp * 256 + ee;
    const bool v0 = (M0 + l31) < Mm;
#pragma unroll
    for (int r = 0; r < 16; ++r) {
        const int d31 = (r & 3) + ((r >> 2) << 3) + (h << 2);
        const size_t o = sb0 + (size_t)d31 * 8;
        u16 hh, ll;
        const float ek = v0 ? __expf(ak[r]) : 0.f;
        const float ev = v0 ? ek * av[r] : 0.f;
        split1(ek, hh, ll); pkb[o] = hh; pkb[o + 512] = ll;
        split1(ev, hh, ll); pkb[o + 1024] = hh; pkb[o + 1536] = ll;
    }
}

// ---------------------------------------------------------------------------
// K2: sq = sigmoid(q0@Wq0^T + q1@Wq1^T). d-split: each wave ONE 32-d tile.
// Grid (8,4,32) x 4 waves = 4096 waves.
// ---------------------------------------------------------------------------
__global__ __launch_bounds__(256) void k2_q(const u16* __restrict__ pkq0,
                                            const u16* __restrict__ pkq1,
                                            const u16* __restrict__ pkw,
                                            float* __restrict__ sq) {
    const int lane = threadIdx.x & 63, wv = threadIdx.x >> 6;
    const int l31 = lane & 31, h = lane >> 5;
    const int b = blockIdx.z;
    const int nt = blockIdx.y * 4 + wv;       // N0 = nt*32
    const int N0 = nt * 32;
    const int dt = blockIdx.x;                // D0 = dt*32
    const int D0 = dt * 32;

    const size_t qa = (size_t)(b * 16 + nt) * 16384 + (size_t)lane * 8;
    const size_t w0 = (size_t)(16 + dt) * 16384 + (size_t)lane * 8;  // Wq0
    const size_t w1 = (size_t)(24 + dt) * 16384 + (size_t)lane * 8;  // Wq1

    floatx16 acc = zero16();

    short8 buf[3][8];
#define K2L(S, DC) { \
    buf[S][0] = *(const short8*)(pkq0 + qa + (size_t)(DC) * 1024); \
    buf[S][1] = *(const short8*)(pkq0 + qa + (size_t)(DC) * 1024 + 512); \
    buf[S][2] = *(const short8*)(pkq1 + qa + (size_t)(DC) * 1024); \
    buf[S][3] = *(const short8*)(pkq1 + qa + (size_t)(DC) * 1024 + 512); \
    buf[S][4] = *(const short8*)(pkw + w0 + (size_t)(DC) * 1024); \
    buf[S][5] = *(const short8*)(pkw + w0 + (size_t)(DC) * 1024 + 512); \
    buf[S][6] = *(const short8*)(pkw + w1 + (size_t)(DC) * 1024); \
    buf[S][7] = *(const short8*)(pkw + w1 + (size_t)(DC) * 1024 + 512); }

    K2L(0, 0)
    K2L(1, 1)
#pragma unroll
    for (int it = 0; it < 16; ++it) {
        if (it + 2 < 16) { K2L((it + 2) % 3, it + 2) }
        const int c = it % 3;
        acc = mfma32(buf[c][0], buf[c][4], acc);
        acc = mfma32(buf[c][0], buf[c][5], acc);
        acc = mfma32(buf[c][1], buf[c][4], acc);
        acc = mfma32(buf[c][2], buf[c][6], acc);
        acc = mfma32(buf[c][2], buf[c][7], acc);
        acc = mfma32(buf[c][3], buf[c][6], acc);
    }
#undef K2L

#pragma unroll
    for (int r = 0; r < 16; ++r) {
        const int n = N0 + (r & 3) + ((r >> 2) << 3) + (h << 2);
        if (n < Nn) {
            const size_t o = ((size_t)b * Nn + n) * Dd + D0 + l31;
            sq[o] = 1.0f / (1.0f + __expf(-acc[r]));
        }
    }
}

// ---------------------------------------------------------------------------
// K3: num/den = expb @ (ekvT/ekT)^T; aafm = sq*num/den -> PKC packed.
// d-split: each wave ONE 32-d tile (2 accs). Grid flat 1024 (b,nt,dh),
// XCD swizzle co-locates all tiles of a batch. 4096 waves (4/SIMD).
// ---------------------------------------------------------------------------
__global__ __launch_bounds__(256) void k3_aafm(const u16* __restrict__ pka,
                                               const u16* __restrict__ pkb,
                                               const float* __restrict__ sq,
                                               u16* __restrict__ pkc) {
    const int i = blockIdx.x;               // 0..1023
    const int x = i & 7, j = i >> 3;        // j 0..127
    const int nt = j & 15;
    const int dh = (j >> 4) & 1;
    const int b = ((j >> 5) << 3) + x;      // all (nt,dh) of b on XCD x
    const int lane = threadIdx.x & 63, wv = threadIdx.x >> 6;
    const int l31 = lane & 31, h = lane >> 5;
    const int N0 = nt << 5;
    const int dt = dh * 4 + wv;             // 0..7

    const size_t abase = (size_t)(b * 16 + nt) * 16384 + (size_t)lane * 8;
    const size_t bb = ((size_t)b * 8 + dt) * 65536 + (size_t)lane * 8;

    floatx16 dn = zero16(), nm = zero16();

    short8 buf[3][5];
#define K3L(S, MC) { \
    buf[S][0] = *(const short8*)(pka + abase + (size_t)(MC) * 512); \
    buf[S][1] = *(const short8*)(pkb + bb + (size_t)(MC) * 2048); \
    buf[S][2] = *(const short8*)(pkb + bb + (size_t)(MC) * 2048 + 512); \
    buf[S][3] = *(const short8*)(pkb + bb + (size_t)(MC) * 2048 + 1024); \
    buf[S][4] = *(const short8*)(pkb + bb + (size_t)(MC) * 2048 + 1536); }

    K3L(0, 0)
    K3L(1, 1)
#pragma unroll
    for (int it = 0; it < 32; ++it) {
        if (it + 2 < 32) { K3L((it + 2) % 3, it + 2) }
        const int c = it % 3;
        dn = mfma32(buf[c][0], buf[c][1], dn);
        dn = mfma32(buf[c][0], buf[c][2], dn);
        nm = mfma32(buf[c][0], buf[c][3], nm);
        nm = mfma32(buf[c][0], buf[c][4], nm);
    }
#undef K3L

    // ---- epilogue: write aafm into PKC packed fragments ----
    const int hp = (l31 >> 3) & 1, ee = l31 & 7;
    const int dcol = dt * 32 + l31;
    const int dc0 = dcol >> 4;
    const size_t cb0 = (size_t)(b * 16 + nt) * 16384 + (size_t)dc0 * 1024
                     + (size_t)hp * 256 + ee;
#pragma unroll
    for (int r = 0; r < 16; ++r) {
        const int n31 = (r & 3) + ((r >> 2) << 3) + (h << 2);
        const int n = N0 + n31;
        if (n < Nn) {
            const size_t so = ((size_t)b * Nn + n) * Dd + dcol;
            const size_t o = cb0 + (size_t)n31 * 8;
            u16 hh, ll;
            const float d0 = dn[r];
            const float w0 = (d0 != 0.f) ? nm[r] / d0 : 0.f;
            split1(sq[so] * w0, hh, ll);
            pkc[o] = hh; pkc[o + 512] = ll;
        }
    }
}

// ---------------------------------------------------------------------------
// K4: logits = 10*tanh((aafm@jobs^T)/16 - a2*ls*cost) + mask, FUSED softmax.
// A (aafm) from PKC, B (jobs) from PKJ -- all loads coalesced. 8 waves.
// ---------------------------------------------------------------------------
__global__ __launch_bounds__(512) void k4_score(const u16* __restrict__ pkc,
                                                const u16* __restrict__ pkj,
                                                const float* __restrict__ cost,
                                                const float* __restrict__ mask,
                                                const float* __restrict__ alpha2,
                                                const float* __restrict__ lsc,
                                                float* __restrict__ out) {
    __shared__ float pred[32][8];
    const int i = blockIdx.x;
    const int x = i & 7, j = i >> 3;
    const int nt = j & 15;
    const int b = ((j >> 4) << 3) + x;
    const int lane = threadIdx.x & 63, wv = threadIdx.x >> 6;  // wv 0..7
    const int l31 = lane & 31, h = lane >> 5;
    const int N0 = nt << 5;
    const float a2ls = alpha2[0] * lsc[0];

    const size_t ab  = (size_t)(b * 16 + nt) * 16384 + (size_t)lane * 8;
    const size_t jb0 = (size_t)(b * 16 + wv * 2) * 16384 + (size_t)lane * 8;
    const size_t jb1 = jb0 + 16384;
    const int m0g = wv * 64 + l31;
    const int m1g = m0g + 32;

    floatx16 acc0 = zero16(), acc1 = zero16();

    short8 buf[3][6];
#define K4L(S, DC) { \
    buf[S][0] = *(const short8*)(pkc + ab  + (size_t)(DC) * 1024); \
    buf[S][1] = *(const short8*)(pkc + ab  + (size_t)(DC) * 1024 + 512); \
    buf[S][2] = *(const short8*)(pkj + jb0 + (size_t)(DC) * 1024); \
    buf[S][3] = *(const short8*)(pkj + jb0 + (size_t)(DC) * 1024 + 512); \
    buf[S][4] = *(const short8*)(pkj + jb1 + (size_t)(DC) * 1024); \
    buf[S][5] = *(const short8*)(pkj + jb1 + (size_t)(DC) * 1024 + 512); }

    K4L(0, 0)
    K4L(1, 1)
#pragma unroll
    for (int it = 0; it < 16; ++it) {
        if (it + 2 < 16) { K4L((it + 2) % 3, it + 2) }
        const int c = it % 3;
        acc0 = mfma32(buf[c][0], buf[c][2], acc0);
        acc0 = mfma32(buf[c][0], buf[c][3], acc0);
        acc0 = mfma32(buf[c][1], buf[c][2], acc0);
        acc1 = mfma32(buf[c][0], buf[c][4], acc1);
        acc1 = mfma32(buf[c][0], buf[c][5], acc1);
        acc1 = mfma32(buf[c][1], buf[c][4], acc1);
    }
#undef K4L

    // ---- epilogue: logits ----
    float lg0[16], lg1[16];
    const size_t cb = (size_t)b * Nn * Mm;
#pragma unroll
    for (int r = 0; r < 16; ++r) {
        const int row = (r & 3) + ((r >> 2) << 3) + (h << 2);
        const int n = N0 + row;
        if (n < Nn) {
            const size_t o = cb + (size_t)n * Mm + m0g;
            lg0[r] = LOGIT_CLIP * fast_tanh(fmaf(-a2ls, cost[o], acc0[r] * INV_SQRT_D)) + mask[o];
            if (m1g < Mm) {
                const size_t o1 = o + 32;
                lg1[r] = LOGIT_CLIP * fast_tanh(fmaf(-a2ls, cost[o1], acc1[r] * INV_SQRT_D)) + mask[o1];
            } else lg1[r] = -1e30f;
        } else { lg0[r] = -1e30f; lg1[r] = -1e30f; }
    }

    // ---- row max: butterfly within 32-lane half, then cross-wave via LDS ----
    float rm[16];
#pragma unroll
    for (int r = 0; r < 16; ++r) rm[r] = fmaxf(lg0[r], lg1[r]);
#pragma unroll
    for (int d = 1; d < 32; d <<= 1)
#pragma unroll
        for (int r = 0; r < 16; ++r) rm[r] = fmaxf(rm[r], __shfl_xor(rm[r], d));
    if (l31 == 0) {
#pragma unroll
        for (int r = 0; r < 16; ++r)
            pred[(r & 3) + ((r >> 2) << 3) + (h << 2)][wv] = rm[r];
    }
    __syncthreads();
    float fm[16];
#pragma unroll
    for (int r = 0; r < 16; ++r) {
        const int row = (r & 3) + ((r >> 2) << 3) + (h << 2);
        float v = pred[row][0];
#pragma unroll
        for (int w = 1; w < 8; ++w) v = fmaxf(v, pred[row][w]);
        fm[r] = v;
    }
    __syncthreads();

    // ---- exp + row sum ----
    float sm[16];
#pragma unroll
    for (int r = 0; r < 16; ++r) {
        lg0[r] = __expf(lg0[r] - fm[r]);
        lg1[r] = __expf(lg1[r] - fm[r]);
        sm[r] = lg0[r] + lg1[r];
    }
#pragma unroll
    for (int d = 1; d < 32; d <<= 1)
#pragma unroll
        for (int r = 0; r < 16; ++r) sm[r] += __shfl_xor(sm[r], d);
    if (l31 == 0) {
#pragma unroll
        for (int r = 0; r < 16; ++r)
            pred[(r & 3) + ((r >> 2) << 3) + (h << 2)][wv] = sm[r];
    }
    __syncthreads();

    // ---- normalize + store ----
#pragma unroll
    for (int r = 0; r < 16; ++r) {
        const int row = (r & 3) + ((r >> 2) << 3) + (h << 2);
        const int n = N0 + row;
        if (n < Nn) {
            float s = pred[row][0];
#pragma unroll
            for (int w = 1; w < 8; ++w) s += pred[row][w];
            const float inv = 1.0f / s;
            const size_t o = cb + (size_t)n * Mm + m0g;
            out[o] = lg0[r] * inv;
            if (m1g < Mm) out[o + 32] = lg1[r] * inv;
        }
    }
}

// ---------------------------------------------------------------------------
extern "C" void kernel_launch(void* const* d_in, const int* in_sizes, int n_in,
                              void* d_out, int out_size, void* d_ws, size_t ws_size,
                              hipStream_t stream) {
    const float* q0        = (const float*)d_in[0];
    const float* jobs      = (const float*)d_in[1];
    const float* q1        = (const float*)d_in[2];
    const float* cost      = (const float*)d_in[3];
    const float* log_scale = (const float*)d_in[4];
    const float* mask      = (const float*)d_in[5];
    const float* Wq0       = (const float*)d_in[6];
    const float* Wq1       = (const float*)d_in[7];
    const float* Wk        = (const float*)d_in[8];
    const float* Wv        = (const float*)d_in[9];
    const float* alpha1    = (const float*)d_in[10];
    const float* alpha2    = (const float*)d_in[11];
    float* out = (float*)d_out;

    const size_t PK_SZ  = (size_t)Bc * 16 * 16384;     //  8,388,608 u16 each
    const size_t PKW_SZ = (size_t)4 * 8 * 16384;       //    524,288 u16
    const size_t PKB_SZ = (size_t)Bc * 8 * 65536;      // 16,777,216 u16

    // ws layout (u16 units):
    // [PKJ | PKQ0 | PKQ1 | PKW | PKB | sq(fp32)]
    // PKA aliases PKQ1 (dead after k2); PKC aliases PKQ0 (dead after k2).
    u16* ws   = (u16*)d_ws;
    u16* pkj  = ws;
    u16* pkq0 = ws + PK_SZ;
    u16* pkq1 = ws + 2 * PK_SZ;
    u16* pkw  = ws + 3 * PK_SZ;
    u16* pkb  = pkw + PKW_SZ;
    float* sq = (float*)(pkb + PKB_SZ);

    u16* pka = pkq1;
    u16* pkc = pkq0;
    (void)ws_size;

    dim3 blk(256);
    k0w_pk<<<dim3(32, 4), blk, 0, stream>>>(Wk, Wv, Wq0, Wq1, pkw);
    k0pk3<<<dim3(2048, 3), blk, 0, stream>>>(jobs, q0, q1, pkj, pkq0, pkq1);
    k1_kv<<<dim3(16, 2, 32), blk, 0, stream>>>(pkj, pkw, pkb);
    k2_q<<<dim3(8, 4, 32), blk, 0, stream>>>(pkq0, pkq1, pkw, sq);
    kexp_pk<<<512, blk, 0, stream>>>(cost, mask, alpha1, log_scale, pka);
    k3_aafm<<<1024, blk, 0, stream>>>(pka, pkb, sq, pkc);
    k4_score<<<512, dim3(512), 0, stream>>>(pkc, pkj, cost, mask,
                                            alpha2, log_scale, out);
}

// Round 4
// 295.847 us; speedup vs baseline: 1.0692x; 1.0692x over previous
//
#include <hip/hip_runtime.h>
#include <math.h>

using u16 = unsigned short;
typedef __attribute__((ext_vector_type(8))) short short8;
typedef __attribute__((ext_vector_type(16))) float floatx16;

constexpr int Bc = 32, Nn = 500, Mm = 500, Dd = 256;
constexpr float LOGIT_CLIP = 10.0f;
constexpr float INV_SQRT_D = 1.0f / 16.0f;

__device__ __forceinline__ floatx16 mfma32(short8 a, short8 b, floatx16 c) {
    return __builtin_amdgcn_mfma_f32_32x32x16_bf16(a, b, c, 0, 0, 0);
}

__device__ __forceinline__ floatx16 zero16() {
    floatx16 v = {0.f,0.f,0.f,0.f,0.f,0.f,0.f,0.f,0.f,0.f,0.f,0.f,0.f,0.f,0.f,0.f};
    return v;
}

// split fp32 x into bf16 hi (RTN) + bf16 lo (RTN of residual): x ~= hi + lo
__device__ __forceinline__ void split1(float x, u16& h, u16& l) {
    unsigned u = __float_as_uint(x);
    unsigned rh = (u + 0x7FFFu + ((u >> 16) & 1u)) & 0xFFFF0000u;
    float fh = __uint_as_float(rh);
    float fl = x - fh;
    unsigned ul = __float_as_uint(fl);
    unsigned rl = ul + 0x7FFFu + ((ul >> 16) & 1u);
    h = (u16)(rh >> 16);
    l = (u16)(rl >> 16);
}

__device__ __forceinline__ u16 bf16rtn(float x) {
    unsigned u = __float_as_uint(x);
    return (u16)((u + 0x7FFFu + ((u >> 16) & 1u)) >> 16);
}

__device__ __forceinline__ float fast_tanh(float x) {
    return 1.0f - 2.0f / (__expf(2.0f * x) + 1.0f);
}

__device__ __forceinline__ void split8(const float4& a, const float4& c,
                                       short8& hv, short8& lv) {
    u16 hh, ll;
    split1(a.x, hh, ll); hv[0] = (short)hh; lv[0] = (short)ll;
    split1(a.y, hh, ll); hv[1] = (short)hh; lv[1] = (short)ll;
    split1(a.z, hh, ll); hv[2] = (short)hh; lv[2] = (short)ll;
    split1(a.w, hh, ll); hv[3] = (short)hh; lv[3] = (short)ll;
    split1(c.x, hh, ll); hv[4] = (short)hh; lv[4] = (short)ll;
    split1(c.y, hh, ll); hv[5] = (short)hh; lv[5] = (short)ll;
    split1(c.z, hh, ll); hv[6] = (short)hh; lv[6] = (short)ll;
    split1(c.w, hh, ll); hv[7] = (short)hh; lv[7] = (short)ll;
}

// ===========================================================================
// Packed fragment layouts (u16 units), fragment = [lane(64)][e(8)] = 512 u16:
//   element (row r, col d) lives at lane=((d>>3)&1)<<5 | (r&31), e = d&7.
//   tile stride: 16 dc-chunks x 2 arr(H/L) x 512 = 16384 u16 per 32-row tile.
// PKW [w(4)][dt(8)]  : weights,  w = {Wk,Wv,Wq0,Wq1}, rows = out-dim.
// PKJ [b][mt(16)]    : jobs,   rows m (zero-padded to 512).
// PKQ0/PKQ1 [b][nt]  : q0/q1,  rows n (zero-padded).
// PKC [b][nt(16)]    : aafm,   rows n (pad rows garbage -> masked in k4).
// PKA [b][nt(16)][mc(32)][512] : expb (n-rows x m-cols), m zero-padded.
// PKB [b][dt(8)][mc(32)][arr(4: ekH,ekL,ekvH,ekvL)][512] : ek/ekv transposed.
// ===========================================================================

// ---------------------------------------------------------------------------
// K0w_pk: weights fp32 -> packed bf16 hi/lo fragments
// ---------------------------------------------------------------------------
__global__ __launch_bounds__(256) void k0w_pk(const float* __restrict__ s0,
                                              const float* __restrict__ s1,
                                              const float* __restrict__ s2,
                                              const float* __restrict__ s3,
                                              u16* __restrict__ pkw) {
    const float* s = blockIdx.y == 0 ? s0 : blockIdx.y == 1 ? s1 :
                     blockIdx.y == 2 ? s2 : s3;
    const int w = blockIdx.y;
    const int flat = (blockIdx.x * 256 + threadIdx.x) * 8;   // 0..65535
    const int i = flat >> 8, j0 = flat & 255;
    float4 a = *(const float4*)&s[flat];
    float4 c = *(const float4*)&s[flat + 4];
    short8 hv, lv;
    split8(a, c, hv, lv);
    const int dt = i >> 5, i31 = i & 31, dc = j0 >> 4, hp = (j0 >> 3) & 1;
    const size_t off = (size_t)(w * 8 + dt) * 16384 + (size_t)dc * 1024
                     + (size_t)((hp << 5) | i31) * 8;
    *(short8*)&pkw[off] = hv;
    *(short8*)&pkw[off + 512] = lv;
}

// ---------------------------------------------------------------------------
// K0pk3: jobs/q0/q1 fp32 -> packed bf16 hi/lo fragments, rows zero-padded 512
// ---------------------------------------------------------------------------
__global__ __launch_bounds__(256) void k0pk3(const float* __restrict__ s0,
                                             const float* __restrict__ s1,
                                             const float* __restrict__ s2,
                                             u16* __restrict__ d0,
                                             u16* __restrict__ d1,
                                             u16* __restrict__ d2) {
    const float* s = blockIdx.y == 0 ? s0 : blockIdx.y == 1 ? s1 : s2;
    u16* d = blockIdx.y == 0 ? d0 : blockIdx.y == 1 ? d1 : d2;
    const int bx = blockIdx.x;           // 0..2047
    const int b = bx >> 6;
    const int chunk = bx & 63;
    const int flat = threadIdx.x * 8;    // 0..2047
    const int lr = flat >> 8;            // 0..7
    const int j0 = flat & 255;
    const int pr = chunk * 8 + lr;       // padded row 0..511
    short8 hv = {0,0,0,0,0,0,0,0}, lv = {0,0,0,0,0,0,0,0};
    if (pr < Nn) {
        const size_t o = ((size_t)b * Nn + pr) * Dd + j0;
        float4 a = *(const float4*)&s[o];
        float4 c = *(const float4*)&s[o + 4];
        split8(a, c, hv, lv);
    }
    const int mt = pr >> 5, r31 = pr & 31;
    const int dc = j0 >> 4, hp = (j0 >> 3) & 1;
    const size_t off = (size_t)(b * 16 + mt) * 16384 + (size_t)dc * 1024
                     + (size_t)((hp << 5) | r31) * 8;
    *(short8*)&d[off] = hv;
    *(short8*)&d[off + 512] = lv;
}

// ---------------------------------------------------------------------------
// KEXP_PK: expb fragment-packed.
// ---------------------------------------------------------------------------
__global__ __launch_bounds__(256) void kexp_pk(const float* __restrict__ cost,
                                               const float* __restrict__ mask,
                                               const float* __restrict__ alpha1,
                                               const float* __restrict__ lsc,
                                               u16* __restrict__ pka) {
    __shared__ u16 tile[32][520];
    const float a1ls = alpha1[0] * lsc[0];
    const int b = blockIdx.x >> 4, nt = blockIdx.x & 15;
    const int t = threadIdx.x;
#pragma unroll
    for (int q = 0; q < 8; ++q) {
        const int flat = (q << 11) + (t << 3);
        const int nl = flat >> 9, m = flat & 511;
        const int n = min(nt * 32 + nl, Nn - 1);
        const size_t o = ((size_t)b * Nn + n) * Mm + m;
        ushort4 w0 = {0, 0, 0, 0}, w1 = {0, 0, 0, 0};
        if (m <= 488) {
            float4 c0 = *(const float4*)&cost[o];
            float4 c1 = *(const float4*)&cost[o + 4];
            float4 k0 = *(const float4*)&mask[o];
            float4 k1 = *(const float4*)&mask[o + 4];
            w0.x = bf16rtn(__expf(fmaf(-a1ls, c0.x, k0.x)));
            w0.y = bf16rtn(__expf(fmaf(-a1ls, c0.y, k0.y)));
            w0.z = bf16rtn(__expf(fmaf(-a1ls, c0.z, k0.z)));
            w0.w = bf16rtn(__expf(fmaf(-a1ls, c0.w, k0.w)));
            w1.x = bf16rtn(__expf(fmaf(-a1ls, c1.x, k1.x)));
            w1.y = bf16rtn(__expf(fmaf(-a1ls, c1.y, k1.y)));
            w1.z = bf16rtn(__expf(fmaf(-a1ls, c1.z, k1.z)));
            w1.w = bf16rtn(__expf(fmaf(-a1ls, c1.w, k1.w)));
        } else if (m == 496) {
            float4 c0 = *(const float4*)&cost[o];
            float4 k0 = *(const float4*)&mask[o];
            w0.x = bf16rtn(__expf(fmaf(-a1ls, c0.x, k0.x)));
            w0.y = bf16rtn(__expf(fmaf(-a1ls, c0.y, k0.y)));
            w0.z = bf16rtn(__expf(fmaf(-a1ls, c0.z, k0.z)));
            w0.w = bf16rtn(__expf(fmaf(-a1ls, c0.w, k0.w)));
        }
        *(ushort4*)&tile[nl][m] = w0;
        *(ushort4*)&tile[nl][m + 4] = w1;
    }
    __syncthreads();
    const int lane = t & 63, wvv = t >> 6;
    const int n31 = lane & 31, hh = lane >> 5;
    const size_t pbase = (size_t)(b * 16 + nt) * 16384 + (size_t)lane * 8;
#pragma unroll
    for (int q = 0; q < 8; ++q) {
        const int mc = wvv * 8 + q;
        short8 v = *(const short8*)&tile[n31][mc * 16 + hh * 8];
        *(short8*)&pka[pbase + (size_t)mc * 512] = v;
    }
}

// ---------------------------------------------------------------------------
// K1: k/v = jobs@Wk^T/Wv^T. m-split: each wave owns ONE 32-m tile x one dt.
// Block shares the pkj tile across its 4 waves (dt varies per wave).
// ---------------------------------------------------------------------------
__global__ __launch_bounds__(256) void k1_kv(const u16* __restrict__ pkj,
                                             const u16* __restrict__ pkw,
                                             u16* __restrict__ pkb) {
    const int lane = threadIdx.x & 63, wv = threadIdx.x >> 6;
    const int l31 = lane & 31, h = lane >> 5;
    const int b = blockIdx.z;
    const int dt = blockIdx.y * 4 + wv;      // 0..7
    const int mt = blockIdx.x;               // 0..15, M0 = mt*32
    const int M0 = mt * 32;

    const size_t wk  = (size_t)dt * 16384 + (size_t)lane * 8;         // Wk
    const size_t wvb = (size_t)(8 + dt) * 16384 + (size_t)lane * 8;   // Wv
    const size_t jb  = (size_t)(b * 16 + mt) * 16384 + (size_t)lane * 8;

    floatx16 ak = zero16(), av = zero16();

    short8 buf[3][6];
#define K1L(S, DC) { \
    buf[S][0] = *(const short8*)(pkw + wk  + (size_t)(DC) * 1024); \
    buf[S][1] = *(const short8*)(pkw + wk  + (size_t)(DC) * 1024 + 512); \
    buf[S][2] = *(const short8*)(pkw + wvb + (size_t)(DC) * 1024); \
    buf[S][3] = *(const short8*)(pkw + wvb + (size_t)(DC) * 1024 + 512); \
    buf[S][4] = *(const short8*)(pkj + jb  + (size_t)(DC) * 1024); \
    buf[S][5] = *(const short8*)(pkj + jb  + (size_t)(DC) * 1024 + 512); }

    K1L(0, 0)
    K1L(1, 1)
#pragma unroll
    for (int it = 0; it < 16; ++it) {
        if (it + 2 < 16) { K1L((it + 2) % 3, it + 2) }
        const int c = it % 3;
        ak = mfma32(buf[c][0], buf[c][4], ak);
        ak = mfma32(buf[c][0], buf[c][5], ak);
        ak = mfma32(buf[c][1], buf[c][4], ak);
        av = mfma32(buf[c][2], buf[c][4], av);
        av = mfma32(buf[c][2], buf[c][5], av);
        av = mfma32(buf[c][3], buf[c][4], av);
    }
#undef K1L

    // ---- epilogue: packed-fragment scatter (zero-fill padded m) ----
    const int hp = (l31 >> 3) & 1, ee = l31 & 7, mcl = l31 >> 4;
    const size_t sb0 = ((size_t)b * 8 + dt) * 65536
                     + (size_t)(mt * 2 + mcl) * 2048 + (size_t)hp * 256 + ee;
    const bool v0 = (M0 + l31) < Mm;
#pragma unroll
    for (int r = 0; r < 16; ++r) {
        const int d31 = (r & 3) + ((r >> 2) << 3) + (h << 2);
        const size_t o = sb0 + (size_t)d31 * 8;
        u16 hh, ll;
        const float ek = v0 ? __expf(ak[r]) : 0.f;
        const float ev = v0 ? ek * av[r] : 0.f;
        split1(ek, hh, ll); pkb[o] = hh; pkb[o + 512] = ll;
        split1(ev, hh, ll); pkb[o + 1024] = hh; pkb[o + 1536] = ll;
    }
}

// ---------------------------------------------------------------------------
// K2: sq = sigmoid(q0@Wq0^T + q1@Wq1^T).
// Block owns ONE (b,nt) A-tile shared by all 4 waves (L1 broadcast);
// wave wv computes dt = {wv, wv+4} (2 accs). A fetched from HBM exactly once.
// Grid (nt=16, b=32) = 512 blocks x 4 waves.
// ---------------------------------------------------------------------------
__global__ __launch_bounds__(256) void k2_q(const u16* __restrict__ pkq0,
                                            const u16* __restrict__ pkq1,
                                            const u16* __restrict__ pkw,
                                            float* __restrict__ sq) {
    const int lane = threadIdx.x & 63, wv = threadIdx.x >> 6;
    const int l31 = lane & 31, h = lane >> 5;
    const int b = blockIdx.y;
    const int nt = blockIdx.x;                // N0 = nt*32
    const int N0 = nt * 32;
    const int dt0 = wv;                       // D cols dt0*32..
    const int dt1 = wv + 4;

    const size_t qa  = (size_t)(b * 16 + nt) * 16384 + (size_t)lane * 8;
    const size_t w00 = (size_t)(16 + dt0) * 16384 + (size_t)lane * 8;  // Wq0 dt0
    const size_t w10 = (size_t)(24 + dt0) * 16384 + (size_t)lane * 8;  // Wq1 dt0
    const size_t w01 = (size_t)(16 + dt1) * 16384 + (size_t)lane * 8;  // Wq0 dt1
    const size_t w11 = (size_t)(24 + dt1) * 16384 + (size_t)lane * 8;  // Wq1 dt1

    floatx16 acc0 = zero16(), acc1 = zero16();

    short8 buf[3][12];
#define K2L(S, DC) { \
    buf[S][0]  = *(const short8*)(pkq0 + qa + (size_t)(DC) * 1024); \
    buf[S][1]  = *(const short8*)(pkq0 + qa + (size_t)(DC) * 1024 + 512); \
    buf[S][2]  = *(const short8*)(pkq1 + qa + (size_t)(DC) * 1024); \
    buf[S][3]  = *(const short8*)(pkq1 + qa + (size_t)(DC) * 1024 + 512); \
    buf[S][4]  = *(const short8*)(pkw + w00 + (size_t)(DC) * 1024); \
    buf[S][5]  = *(const short8*)(pkw + w00 + (size_t)(DC) * 1024 + 512); \
    buf[S][6]  = *(const short8*)(pkw + w10 + (size_t)(DC) * 1024); \
    buf[S][7]  = *(const short8*)(pkw + w10 + (size_t)(DC) * 1024 + 512); \
    buf[S][8]  = *(const short8*)(pkw + w01 + (size_t)(DC) * 1024); \
    buf[S][9]  = *(const short8*)(pkw + w01 + (size_t)(DC) * 1024 + 512); \
    buf[S][10] = *(const short8*)(pkw + w11 + (size_t)(DC) * 1024); \
    buf[S][11] = *(const short8*)(pkw + w11 + (size_t)(DC) * 1024 + 512); }

    K2L(0, 0)
    K2L(1, 1)
#pragma unroll
    for (int it = 0; it < 16; ++it) {
        if (it + 2 < 16) { K2L((it + 2) % 3, it + 2) }
        const int c = it % 3;
        acc0 = mfma32(buf[c][0], buf[c][4], acc0);
        acc0 = mfma32(buf[c][0], buf[c][5], acc0);
        acc0 = mfma32(buf[c][1], buf[c][4], acc0);
        acc0 = mfma32(buf[c][2], buf[c][6], acc0);
        acc0 = mfma32(buf[c][2], buf[c][7], acc0);
        acc0 = mfma32(buf[c][3], buf[c][6], acc0);
        acc1 = mfma32(buf[c][0], buf[c][8], acc1);
        acc1 = mfma32(buf[c][0], buf[c][9], acc1);
        acc1 = mfma32(buf[c][1], buf[c][8], acc1);
        acc1 = mfma32(buf[c][2], buf[c][10], acc1);
        acc1 = mfma32(buf[c][2], buf[c][11], acc1);
        acc1 = mfma32(buf[c][3], buf[c][10], acc1);
    }
#undef K2L

#pragma unroll
    for (int r = 0; r < 16; ++r) {
        const int n = N0 + (r & 3) + ((r >> 2) << 3) + (h << 2);
        if (n < Nn) {
            const size_t o = ((size_t)b * Nn + n) * Dd + l31;
            sq[o + dt0 * 32] = 1.0f / (1.0f + __expf(-acc0[r]));
            sq[o + dt1 * 32] = 1.0f / (1.0f + __expf(-acc1[r]));
        }
    }
}

// ---------------------------------------------------------------------------
// K3: num/den = expb @ (ekvT/ekT)^T; aafm = sq*num/den -> PKC packed.
// d-split: each wave ONE 32-d tile (2 accs). Grid flat 1024 (b,nt,dh),
// XCD swizzle co-locates all tiles of a batch. 4096 waves (4/SIMD).
// ---------------------------------------------------------------------------
__global__ __launch_bounds__(256) void k3_aafm(const u16* __restrict__ pka,
                                               const u16* __restrict__ pkb,
                                               const float* __restrict__ sq,
                                               u16* __restrict__ pkc) {
    const int i = blockIdx.x;               // 0..1023
    const int x = i & 7, j = i >> 3;        // j 0..127
    const int nt = j & 15;
    const int dh = (j >> 4) & 1;
    const int b = ((j >> 5) << 3) + x;      // all (nt,dh) of b on XCD x
    const int lane = threadIdx.x & 63, wv = threadIdx.x >> 6;
    const int l31 = lane & 31, h = lane >> 5;
    const int N0 = nt << 5;
    const int dt = dh * 4 + wv;             // 0..7

    const size_t abase = (size_t)(b * 16 + nt) * 16384 + (size_t)lane * 8;
    const size_t bb = ((size_t)b * 8 + dt) * 65536 + (size_t)lane * 8;

    floatx16 dn = zero16(), nm = zero16();

    short8 buf[3][5];
#define K3L(S, MC) { \
    buf[S][0] = *(const short8*)(pka + abase + (size_t)(MC) * 512); \
    buf[S][1] = *(const short8*)(pkb + bb + (size_t)(MC) * 2048); \
    buf[S][2] = *(const short8*)(pkb + bb + (size_t)(MC) * 2048 + 512); \
    buf[S][3] = *(const short8*)(pkb + bb + (size_t)(MC) * 2048 + 1024); \
    buf[S][4] = *(const short8*)(pkb + bb + (size_t)(MC) * 2048 + 1536); }

    K3L(0, 0)
    K3L(1, 1)
#pragma unroll
    for (int it = 0; it < 32; ++it) {
        if (it + 2 < 32) { K3L((it + 2) % 3, it + 2) }
        const int c = it % 3;
        dn = mfma32(buf[c][0], buf[c][1], dn);
        dn = mfma32(buf[c][0], buf[c][2], dn);
        nm = mfma32(buf[c][0], buf[c][3], nm);
        nm = mfma32(buf[c][0], buf[c][4], nm);
    }
#undef K3L

    // ---- epilogue: write aafm into PKC packed fragments ----
    const int hp = (l31 >> 3) & 1, ee = l31 & 7;
    const int dcol = dt * 32 + l31;
    const int dc0 = dcol >> 4;
    const size_t cb0 = (size_t)(b * 16 + nt) * 16384 + (size_t)dc0 * 1024
                     + (size_t)hp * 256 + ee;
#pragma unroll
    for (int r = 0; r < 16; ++r) {
        const int n31 = (r & 3) + ((r >> 2) << 3) + (h << 2);
        const int n = N0 + n31;
        if (n < Nn) {
            const size_t so = ((size_t)b * Nn + n) * Dd + dcol;
            const size_t o = cb0 + (size_t)n31 * 8;
            u16 hh, ll;
            const float d0 = dn[r];
            const float w0 = (d0 != 0.f) ? nm[r] / d0 : 0.f;
            split1(sq[so] * w0, hh, ll);
            pkc[o] = hh; pkc[o + 512] = ll;
        }
    }
}

// ---------------------------------------------------------------------------
// K4: logits = 10*tanh((aafm@jobs^T)/16 - a2*ls*cost) + mask, FUSED softmax.
// A (aafm) from PKC, B (jobs) from PKJ -- all loads coalesced. 8 waves.
// ---------------------------------------------------------------------------
__global__ __launch_bounds__(512) void k4_score(const u16* __restrict__ pkc,
                                                const u16* __restrict__ pkj,
                                                const float* __restrict__ cost,
                                                const float* __restrict__ mask,
                                                const float* __restrict__ alpha2,
                                                const float* __restrict__ lsc,
                                                float* __restrict__ out) {
    __shared__ float pred[32][8];
    const int i = blockIdx.x;
    const int x = i & 7, j = i >> 3;
    const int nt = j & 15;
    const int b = ((j >> 4) << 3) + x;
    const int lane = threadIdx.x & 63, wv = threadIdx.x >> 6;  // wv 0..7
    const int l31 = lane & 31, h = lane >> 5;
    const int N0 = nt << 5;
    const float a2ls = alpha2[0] * lsc[0];

    const size_t ab  = (size_t)(b * 16 + nt) * 16384 + (size_t)lane * 8;
    const size_t jb0 = (size_t)(b * 16 + wv * 2) * 16384 + (size_t)lane * 8;
    const size_t jb1 = jb0 + 16384;
    const int m0g = wv * 64 + l31;
    const int m1g = m0g + 32;

    floatx16 acc0 = zero16(), acc1 = zero16();

    short8 buf[3][6];
#define K4L(S, DC) { \
    buf[S][0] = *(const short8*)(pkc + ab  + (size_t)(DC) * 1024); \
    buf[S][1] = *(const short8*)(pkc + ab  + (size_t)(DC) * 1024 + 512); \
    buf[S][2] = *(const short8*)(pkj + jb0 + (size_t)(DC) * 1024); \
    buf[S][3] = *(const short8*)(pkj + jb0 + (size_t)(DC) * 1024 + 512); \
    buf[S][4] = *(const short8*)(pkj + jb1 + (size_t)(DC) * 1024); \
    buf[S][5] = *(const short8*)(pkj + jb1 + (size_t)(DC) * 1024 + 512); }

    K4L(0, 0)
    K4L(1, 1)
#pragma unroll
    for (int it = 0; it < 16; ++it) {
        if (it + 2 < 16) { K4L((it + 2) % 3, it + 2) }
        const int c = it % 3;
        acc0 = mfma32(buf[c][0], buf[c][2], acc0);
        acc0 = mfma32(buf[c][0], buf[c][3], acc0);
        acc0 = mfma32(buf[c][1], buf[c][2], acc0);
        acc1 = mfma32(buf[c][0], buf[c][4], acc1);
        acc1 = mfma32(buf[c][0], buf[c][5], acc1);
        acc1 = mfma32(buf[c][1], buf[c][4], acc1);
    }
#undef K4L

    // ---- epilogue: logits ----
    float lg0[16], lg1[16];
    const size_t cb = (size_t)b * Nn * Mm;
#pragma unroll
    for (int r = 0; r < 16; ++r) {
        const int row = (r & 3) + ((r >> 2) << 3) + (h << 2);
        const int n = N0 + row;
        if (n < Nn) {
            const size_t o = cb + (size_t)n * Mm + m0g;
            lg0[r] = LOGIT_CLIP * fast_tanh(fmaf(-a2ls, cost[o], acc0[r] * INV_SQRT_D)) + mask[o];
            if (m1g < Mm) {
                const size_t o1 = o + 32;
                lg1[r] = LOGIT_CLIP * fast_tanh(fmaf(-a2ls, cost[o1], acc1[r] * INV_SQRT_D)) + mask[o1];
            } else lg1[r] = -1e30f;
        } else { lg0[r] = -1e30f; lg1[r] = -1e30f; }
    }

    // ---- row max: butterfly within 32-lane half, then cross-wave via LDS ----
    float rm[16];
#pragma unroll
    for (int r = 0; r < 16; ++r) rm[r] = fmaxf(lg0[r], lg1[r]);
#pragma unroll
    for (int d = 1; d < 32; d <<= 1)
#pragma unroll
        for (int r = 0; r < 16; ++r) rm[r] = fmaxf(rm[r], __shfl_xor(rm[r], d));
    if (l31 == 0) {
#pragma unroll
        for (int r = 0; r < 16; ++r)
            pred[(r & 3) + ((r >> 2) << 3) + (h << 2)][wv] = rm[r];
    }
    __syncthreads();
    float fm[16];
#pragma unroll
    for (int r = 0; r < 16; ++r) {
        const int row = (r & 3) + ((r >> 2) << 3) + (h << 2);
        float v = pred[row][0];
#pragma unroll
        for (int w = 1; w < 8; ++w) v = fmaxf(v, pred[row][w]);
        fm[r] = v;
    }
    __syncthreads();

    // ---- exp + row sum ----
    float sm[16];
#pragma unroll
    for (int r = 0; r < 16; ++r) {
        lg0[r] = __expf(lg0[r] - fm[r]);
        lg1[r] = __expf(lg1[r] - fm[r]);
        sm[r] = lg0[r] + lg1[r];
    }
#pragma unroll
    for (int d = 1; d < 32; d <<= 1)
#pragma unroll
        for (int r = 0; r < 16; ++r) sm[r] += __shfl_xor(sm[r], d);
    if (l31 == 0) {
#pragma unroll
        for (int r = 0; r < 16; ++r)
            pred[(r & 3) + ((r >> 2) << 3) + (h << 2)][wv] = sm[r];
    }
    __syncthreads();

    // ---- normalize + store ----
#pragma unroll
    for (int r = 0; r < 16; ++r) {
        const int row = (r & 3) + ((r >> 2) << 3) + (h << 2);
        const int n = N0 + row;
        if (n < Nn) {
            float s = pred[row][0];
#pragma unroll
            for (int w = 1; w < 8; ++w) s += pred[row][w];
            const float inv = 1.0f / s;
            const size_t o = cb + (size_t)n * Mm + m0g;
            out[o] = lg0[r] * inv;
            if (m1g < Mm) out[o + 32] = lg1[r] * inv;
        }
    }
}

// ---------------------------------------------------------------------------
extern "C" void kernel_launch(void* const* d_in, const int* in_sizes, int n_in,
                              void* d_out, int out_size, void* d_ws, size_t ws_size,
                              hipStream_t stream) {
    const float* q0        = (const float*)d_in[0];
    const float* jobs      = (const float*)d_in[1];
    const float* q1        = (const float*)d_in[2];
    const float* cost      = (const float*)d_in[3];
    const float* log_scale = (const float*)d_in[4];
    const float* mask      = (const float*)d_in[5];
    const float* Wq0       = (const float*)d_in[6];
    const float* Wq1       = (const float*)d_in[7];
    const float* Wk        = (const float*)d_in[8];
    const float* Wv        = (const float*)d_in[9];
    const float* alpha1    = (const float*)d_in[10];
    const float* alpha2    = (const float*)d_in[11];
    float* out = (float*)d_out;

    const size_t PK_SZ  = (size_t)Bc * 16 * 16384;     //  8,388,608 u16 each
    const size_t PKW_SZ = (size_t)4 * 8 * 16384;       //    524,288 u16
    const size_t PKB_SZ = (size_t)Bc * 8 * 65536;      // 16,777,216 u16

    // ws layout (u16 units):
    // [PKJ | PKQ0 | PKQ1 | PKW | PKB | sq(fp32)]
    // PKA aliases PKQ1 (dead after k2); PKC aliases PKQ0 (dead after k2).
    u16* ws   = (u16*)d_ws;
    u16* pkj  = ws;
    u16* pkq0 = ws + PK_SZ;
    u16* pkq1 = ws + 2 * PK_SZ;
    u16* pkw  = ws + 3 * PK_SZ;
    u16* pkb  = pkw + PKW_SZ;
    float* sq = (float*)(pkb + PKB_SZ);

    u16* pka = pkq1;
    u16* pkc = pkq0;
    (void)ws_size;

    dim3 blk(256);
    k0w_pk<<<dim3(32, 4), blk, 0, stream>>>(Wk, Wv, Wq0, Wq1, pkw);
    k0pk3<<<dim3(2048, 3), blk, 0, stream>>>(jobs, q0, q1, pkj, pkq0, pkq1);
    k1_kv<<<dim3(16, 2, 32), blk, 0, stream>>>(pkj, pkw, pkb);
    k2_q<<<dim3(16, 32), blk, 0, stream>>>(pkq0, pkq1, pkw, sq);
    kexp_pk<<<512, blk, 0, stream>>>(cost, mask, alpha1, log_scale, pka);
    k3_aafm<<<1024, blk, 0, stream>>>(pka, pkb, sq, pkc);
    k4_score<<<512, dim3(512), 0, stream>>>(pkc, pkj, cost, mask,
                                            alpha2, log_scale, out);
}